// Round 4
// baseline (98.537 us; speedup 1.0000x reference)
//
#include <hip/hip_runtime.h>
#include <math.h>

#define N 512
#define D 256
#define LOSS_MARGIN 0.3f
#define STRIDE 260      // 256+4 floats: 16B-aligned LDS rows; 16 rows -> 2-way conflict (free)
#define POISON 0xAAAAAAAAu
#define NBLOCKS 512u

// Fused kernel: grid (32,16) = 512 blocks (2/CU), block 256.
// Tile = 16 anchors (LDS) x 32 candidates (global/L2). Thread (il=t&15, jl=t>>4)
// computes dist(il, jl) and dist(il, jl+16). Per-row hardest-pos/neg merged across
// blocks via int atomicMax on order-preserving float bits (dist >= 0).
// 512th block to finish runs the hinge+mean finisher.
__global__ __launch_bounds__(256) void triplet_fused_kernel(
    const float* __restrict__ X,      // (512,256)
    const int*  __restrict__ tgt,     // (512,)
    int* __restrict__ gap,            // (512,) max bits(ap); init 0xAAAAAAAA (< 0)
    int* __restrict__ gan,            // (512,) max (0x7FFFFFFF - bits(an)); init poison
    unsigned* __restrict__ counter,   // init 0xAAAAAAAA
    float* __restrict__ out)
{
    const int it = blockIdx.x, jt = blockIdx.y, t = threadIdx.x;
    const int i0 = it * 16, j0 = jt * 32;

    __shared__ float xi[16 * STRIDE];        // 16.6 KB
    __shared__ float sap[4][16], san[4][16];
    __shared__ int amLast;

    // Stage 16 anchor rows, coalesced float4.
    #pragma unroll
    for (int k = 0; k < 4; ++k) {
        const int f = t + 256 * k;           // 0..1023 float4 slots
        const int r = f >> 6, c = (f & 63) << 2;
        *(float4*)&xi[r * STRIDE + c] = *(const float4*)(X + (i0 + r) * D + c);
    }
    __syncthreads();

    const int il = t & 15, jl = t >> 4;
    const int ci  = tgt[i0 + il];
    const int cj0 = tgt[j0 + jl];
    const int cj1 = tgt[j0 + jl + 16];

    const float4* ap_ = (const float4*)&xi[il * STRIDE];            // LDS, 2-way free
    const float4* b0p = (const float4*)(X + (j0 + jl) * D);         // L2-resident
    const float4* b1p = (const float4*)(X + (j0 + jl + 16) * D);

    float4 s0 = {0,0,0,0}, s1 = {0,0,0,0};
    #pragma unroll 4
    for (int d = 0; d < D / 4; ++d) {
        const float4 a = ap_[d];
        const float4 b = b0p[d], c = b1p[d];
        s0.x += fabsf(a.x-b.x); s0.y += fabsf(a.y-b.y);
        s0.z += fabsf(a.z-b.z); s0.w += fabsf(a.w-b.w);
        s1.x += fabsf(a.x-c.x); s1.y += fabsf(a.y-c.y);
        s1.z += fabsf(a.z-c.z); s1.w += fabsf(a.w-c.w);
    }
    const float inv = 1.0f / (float)D;
    const float d0 = (s0.x+s0.y+s0.z+s0.w) * inv;
    const float d1 = (s1.x+s1.y+s1.z+s1.w) * inv;

    float ap = fmaxf(cj0==ci ? d0 : -INFINITY, cj1==ci ? d1 : -INFINITY);
    float an = fminf(cj0==ci ?  INFINITY : d0, cj1==ci ?  INFINITY : d1);

    // Reduce over in-wave jl (lane bits 4-5).
    ap = fmaxf(ap, __shfl_xor(ap, 16, 64)); an = fminf(an, __shfl_xor(an, 16, 64));
    ap = fmaxf(ap, __shfl_xor(ap, 32, 64)); an = fminf(an, __shfl_xor(an, 32, 64));

    const int w = t >> 6, wl = t & 63;
    if (wl < 16) { sap[w][wl] = ap; san[w][wl] = an; }
    __syncthreads();

    if (t < 16) {
        const float A  = fmaxf(fmaxf(sap[0][t], sap[1][t]), fmaxf(sap[2][t], sap[3][t]));
        const float Nn = fminf(fminf(san[0][t], san[1][t]), fminf(san[2][t], san[3][t]));
        // dist >= 0 => float bits order-preserving as int. Map min -> max.
        atomicMax(&gap[i0 + t], __float_as_int(A));
        atomicMax(&gan[i0 + t], 0x7FFFFFFF - __float_as_int(Nn));
    }
    __threadfence();                         // release our atomics
    __syncthreads();
    if (t == 0) {
        const unsigned old = atomicAdd(counter, 1u);
        amLast = (old == POISON + (NBLOCKS - 1u));
    }
    __syncthreads();
    if (!amLast) return;

    // ---- last block: finisher ----
    __threadfence();                         // acquire all blocks' atomics
    float v = 0.f;
    #pragma unroll
    for (int rr = 0; rr < 2; ++rr) {
        const int i = t + rr * 256;
        const int apb = __hip_atomic_load(&gap[i], __ATOMIC_RELAXED, __HIP_MEMORY_SCOPE_AGENT);
        const int anm = __hip_atomic_load(&gan[i], __ATOMIC_RELAXED, __HIP_MEMORY_SCOPE_AGENT);
        const float A  = __int_as_float(apb);
        const float Nn = __int_as_float(0x7FFFFFFF - anm);
        v += fmaxf(A - Nn + LOSS_MARGIN, 0.0f);
    }
    #pragma unroll
    for (int off = 32; off >= 1; off >>= 1) v += __shfl_down(v, off, 64);
    __shared__ float s[4];
    if (wl == 0) s[w] = v;
    __syncthreads();
    if (t == 0) out[0] = (s[0] + s[1] + s[2] + s[3]) * (1.0f / (float)N);
}

extern "C" void kernel_launch(void* const* d_in, const int* in_sizes, int n_in,
                              void* d_out, int out_size, void* d_ws, size_t ws_size,
                              hipStream_t stream) {
    const float* X   = (const float*)d_in[0];
    const int*   tgt = (const int*)d_in[1];
    float* out = (float*)d_out;

    int* gap = (int*)d_ws;                               // 512 ints
    int* gan = gap + N;                                  // 512 ints
    unsigned* counter = (unsigned*)((char*)d_ws + 4096); // 1 uint

    // Self-poison the 4.1 KB we use: deterministic base for atomicMax + counter,
    // independent of harness poison semantics. Memset nodes are graph-capturable.
    hipMemsetAsync(d_ws, 0xAA, 4100, stream);

    dim3 grid(32, 16);
    triplet_fused_kernel<<<grid, 256, 0, stream>>>(X, tgt, gap, gan, counter, out);
}

// Round 5
// 67.339 us; speedup vs baseline: 1.4633x; 1.4633x over previous
//
#include <hip/hip_runtime.h>
#include <math.h>

#define N 512
#define D 256
#define LOSS_MARGIN 0.3f
#define STRIDE 260   // 256+4 floats: 16B-aligned LDS rows; 2-way bank alias only (free)

// k1: grid (32,16) = 512 blocks (2/CU), block 256.
// Tile = 16 anchors (LDS-staged) x 32 candidates (read direct from L2).
// Thread (il=t&15, jl=t>>4) computes dist(il, jl) and dist(il, jl+16).
// Feed is split across pipes: anchors on LDS port (2-way, free), candidates on
// VMEM port (4 lines + 16-lane broadcast per wave instr). No global atomics —
// per-(i,jtile) partials go to d_ws; R4 showed same-address cross-XCD atomics
// cost ~40 us at this block count.
__global__ __launch_bounds__(256) void triplet_tile_kernel(
    const float* __restrict__ X,    // (512,256)
    const int*  __restrict__ tgt,   // (512,)
    float* __restrict__ wap,        // (16,512) per-jtile hardest-positive
    float* __restrict__ wan)        // (16,512) per-jtile hardest-negative
{
    const int it = blockIdx.x, jt = blockIdx.y, t = threadIdx.x;
    const int i0 = it * 16, j0 = jt * 32;

    __shared__ float xi[16 * STRIDE];        // 16.6 KB
    __shared__ float sap[4][16], san[4][16];

    // Stage 16 anchor rows, fully coalesced float4 loads.
    #pragma unroll
    for (int k = 0; k < 4; ++k) {
        const int f = t + 256 * k;           // 0..1023 float4 slots
        const int r = f >> 6, c = (f & 63) << 2;
        *(float4*)&xi[r * STRIDE + c] = *(const float4*)(X + (i0 + r) * D + c);
    }
    __syncthreads();

    const int il = t & 15, jl = t >> 4;
    const int ci  = tgt[i0 + il];
    const int cj0 = tgt[j0 + jl];
    const int cj1 = tgt[j0 + jl + 16];

    const float4* a_p = (const float4*)&xi[il * STRIDE];        // LDS
    const float4* b0p = (const float4*)(X + (j0 + jl) * D);     // L2-resident
    const float4* b1p = (const float4*)(X + (j0 + jl + 16) * D);

    float4 s0 = {0,0,0,0}, s1 = {0,0,0,0};
    #pragma unroll 8
    for (int d = 0; d < D / 4; ++d) {
        const float4 a = a_p[d];
        const float4 b = b0p[d], c = b1p[d];
        s0.x += fabsf(a.x-b.x); s0.y += fabsf(a.y-b.y);
        s0.z += fabsf(a.z-b.z); s0.w += fabsf(a.w-b.w);
        s1.x += fabsf(a.x-c.x); s1.y += fabsf(a.y-c.y);
        s1.z += fabsf(a.z-c.z); s1.w += fabsf(a.w-c.w);
    }
    const float inv = 1.0f / (float)D;
    const float d0 = (s0.x+s0.y+s0.z+s0.w) * inv;
    const float d1 = (s1.x+s1.y+s1.z+s1.w) * inv;

    float ap = fmaxf(cj0==ci ? d0 : -INFINITY, cj1==ci ? d1 : -INFINITY);
    float an = fminf(cj0==ci ?  INFINITY : d0, cj1==ci ?  INFINITY : d1);

    // Reduce over the 4 jl values resident in this wave (lane bits 4-5).
    ap = fmaxf(ap, __shfl_xor(ap, 16, 64)); an = fminf(an, __shfl_xor(an, 16, 64));
    ap = fmaxf(ap, __shfl_xor(ap, 32, 64)); an = fminf(an, __shfl_xor(an, 32, 64));

    const int w = t >> 6, wl = t & 63;
    if (wl < 16) { sap[w][wl] = ap; san[w][wl] = an; }
    __syncthreads();

    if (t < 16) {
        const float A  = fmaxf(fmaxf(sap[0][t], sap[1][t]), fmaxf(sap[2][t], sap[3][t]));
        const float Nn = fminf(fminf(san[0][t], san[1][t]), fminf(san[2][t], san[3][t]));
        wap[jt * N + i0 + t] = A;
        wan[jt * N + i0 + t] = Nn;
    }
}

// k2: one block, 512 threads — combine 16 j-tile partials per row, hinge, mean.
__global__ __launch_bounds__(512) void triplet_final_kernel(
    const float* __restrict__ wap, const float* __restrict__ wan,
    float* __restrict__ out)
{
    const int t = threadIdx.x;   // row 0..511
    float ap = -INFINITY, an = INFINITY;
    #pragma unroll
    for (int jt = 0; jt < 16; ++jt) {
        ap = fmaxf(ap, wap[jt * N + t]);    // coalesced
        an = fminf(an, wan[jt * N + t]);
    }
    float v = fmaxf(ap - an + LOSS_MARGIN, 0.0f);
    #pragma unroll
    for (int off = 32; off >= 1; off >>= 1) v += __shfl_down(v, off, 64);
    __shared__ float s[8];
    if ((t & 63) == 0) s[t >> 6] = v;
    __syncthreads();
    if (t == 0) {
        float tot = 0.f;
        #pragma unroll
        for (int w = 0; w < 8; ++w) tot += s[w];
        out[0] = tot * (1.0f / (float)N);
    }
}

extern "C" void kernel_launch(void* const* d_in, const int* in_sizes, int n_in,
                              void* d_out, int out_size, void* d_ws, size_t ws_size,
                              hipStream_t stream) {
    const float* X   = (const float*)d_in[0];
    const int*   tgt = (const int*)d_in[1];
    float* out = (float*)d_out;
    float* wap = (float*)d_ws;          // 16*512 floats
    float* wan = wap + 16 * N;          // 16*512 floats

    dim3 grid(32, 16);
    triplet_tile_kernel<<<grid, 256, 0, stream>>>(X, tgt, wap, wan);
    triplet_final_kernel<<<1, N, 0, stream>>>(wap, wan, out);
}